// Round 22
// baseline (116.166 us; speedup 1.0000x reference)
//
#include <hip/hip_runtime.h>
#include <hip/hip_bf16.h>
#include <math.h>

#define Hd   512
#define FPd  256
#define Ed   512
#define NFd  768
#define Ld   512
#define Bd   32
#define K2H  1024            // 2H
#define Nd   1024            // NF + FP
#define Md   (Ld * Bd)       // 16384

typedef _Float16 f16x8  __attribute__((ext_vector_type(8)));
typedef _Float16 f16x4  __attribute__((ext_vector_type(4)));
typedef float    f32x4  __attribute__((ext_vector_type(4)));
typedef float    f32x16 __attribute__((ext_vector_type(16)));

// ---------------------------------------------------------------------------
// Kernel 1: W_big build + fp16 frag repack (R20-verified, unchanged).
// Frag layout: fo = ((ntile*64 + t)*64 + lane)*8,
//   n = ntile*32+(lane&31), k = t*16+(lane>>5)*8+j.
// ---------------------------------------------------------------------------
__global__ __launch_bounds__(256)
void build_wpack(const float* __restrict__ F,
                 const float* __restrict__ Wf,
                 const float* __restrict__ V,
                 const float* __restrict__ Wl,
                 _Float16* __restrict__ Bh) {
    __shared__ float fs[32][68];
    __shared__ float ws[64][36];
    __shared__ float wtile[32][36];
    const int tid = threadIdx.x;
    const int kx  = blockIdx.x;         // 0..31
    const int ny  = blockIdx.y;         // 0..31
    const int n0  = ny * 32;
    const int kl  = tid & 31;
    const int ty  = tid >> 5;           // 0..7 -> 4 rows each

    const float* src;  const float* wsrc;
    if (n0 < NFd) { src = F + (size_t)n0 * Ed;          wsrc = Wf; }
    else          { src = V + (size_t)(n0 - NFd) * Hd;  wsrc = Wl; }
    const float* wbase = wsrc + kx * 32;

    float acc[4];
#pragma unroll
    for (int i = 0; i < 4; i++) acc[i] = 0.f;

    for (int e0 = 0; e0 < 512; e0 += 64) {
#pragma unroll
        for (int rep = 0; rep < 2; rep++) {
            int idx = rep * 256 + tid;
            int i   = idx >> 4;
            int q   = idx & 15;
            float4 v4 = *(const float4*)(src + (size_t)i * 512 + e0 + q * 4);
            *(float4*)(&fs[i][q * 4]) = v4;
        }
#pragma unroll
        for (int rep = 0; rep < 2; rep++) {
            int idx = rep * 256 + tid;
            int e   = idx >> 3;
            int q   = idx & 7;
            float4 v4 = *(const float4*)(wbase + (size_t)(e0 + e) * K2H + q * 4);
            *(float4*)(&ws[e][q * 4]) = v4;
        }
        __syncthreads();
#pragma unroll 4
        for (int kk = 0; kk < 64; kk += 4) {
            float w0 = ws[kk + 0][kl];
            float w1 = ws[kk + 1][kl];
            float w2 = ws[kk + 2][kl];
            float w3 = ws[kk + 3][kl];
#pragma unroll
            for (int i = 0; i < 4; i++) {
                float4 f4 = *(const float4*)(&fs[ty * 4 + i][kk]);
                acc[i] += f4.x * w0 + f4.y * w1 + f4.z * w2 + f4.w * w3;
            }
        }
        __syncthreads();
    }
#pragma unroll
    for (int i = 0; i < 4; i++) wtile[ty * 4 + i][kl] = acc[i];
    __syncthreads();
    if (tid < 128) {
        const int lane = tid & 63;
        const int ksl  = tid >> 6;            // 0..1
        const int nl   = lane & 31;
        const int kf   = ksl * 16 + (lane >> 5) * 8;
        float w[8];
        *(float4*)(w)     = *(const float4*)(&wtile[nl][kf]);
        *(float4*)(w + 4) = *(const float4*)(&wtile[nl][kf + 4]);
        f16x8 h;
#pragma unroll
        for (int j = 0; j < 8; j++) h[j] = (_Float16)w[j];
        const size_t fo = ((size_t)((ny * 64) + (kx * 2 + ksl)) * 64 + lane) * 8;
        *(f16x8*)(Bh + fo) = h;
    }
}

// ---------------------------------------------------------------------------
// Kernel 1b: bias_big[n]
// ---------------------------------------------------------------------------
__global__ __launch_bounds__(64)
void build_bias(const float* __restrict__ F, const float* __restrict__ bf,
                const float* __restrict__ V, const float* __restrict__ bl,
                float* __restrict__ bias) {
    const int n    = blockIdx.x;
    const int lane = threadIdx.x;
    const float* row; const float* bsrc;
    if (n < NFd) { row = F + (size_t)n * Ed;          bsrc = bf; }
    else         { row = V + (size_t)(n - NFd) * Hd;  bsrc = bl; }
    float a = 0.f;
#pragma unroll
    for (int rep = 0; rep < 8; rep++) {
        int e = rep * 64 + lane;
        a += row[e] * bsrc[e];
    }
#pragma unroll
    for (int off = 1; off < 64; off <<= 1) a += __shfl_xor(a, off);
    if (lane == 0) bias[n] = a;
}

// ---------------------------------------------------------------------------
// Kernel 2: GEMM (fp16 x fp16) + fused softmax + direct transposed store.
// R22 change: 512 blocks x 512 thr (8 waves) -> 2 INDEPENDENT blocks/CU.
// Block = 32 rows (fixed b, 32 l) x N=1024; wave wn covers cols wn*128
// (4 nt of 32), acc[4] = 64 AGPR; launch_bounds(512,4) pins 128-reg
// budget so both blocks co-reside (16 waves/CU). Barriers sync only 8
// waves; the sibling block's waves run through the drain (TLP replaces
// the dropped 2-deep B ILP pipeline). NT enc loads; frag-major
// conflict-free LDS (1 plane, 4KB/buf); setprio around MFMA cluster.
// ---------------------------------------------------------------------------
__global__ __launch_bounds__(512, 4)
void gemm_direct(const float* __restrict__ enc,
                 const _Float16* __restrict__ Bh,
                 const float* __restrict__ bias,
                 float* __restrict__ out) {
    __shared__ char AsB[2][4096];      // per buf: [kk:4][slot:64]*16B
    __shared__ float red[8][32];
    __shared__ float redc[32];

    const int tid  = threadIdx.x;
    const int lane = tid & 63;
    const int wn   = tid >> 6;         // wave 0..7 -> 128-col block
    const int hf   = lane >> 5;
    const int l31  = lane & 31;
    const int b    = blockIdx.x >> 4;  // 0..31
    const int l0   = (blockIdx.x & 15) * 32;

    // bias folded into accumulator init
    float bv[4];
#pragma unroll
    for (int nt = 0; nt < 4; nt++) bv[nt] = bias[wn * 128 + nt * 32 + l31];
    f32x16 acc[4];
#pragma unroll
    for (int nt = 0; nt < 4; nt++)
#pragma unroll
        for (int r = 0; r < 16; r++) acc[nt][r] = bv[nt];

    // staging map: thread -> (row = tid>>4 in 0..31, 4 k at (tid&15)*4)
    const int srow = tid >> 4;
    const int skf  = (tid & 15) * 4;
    const float* gA = enc + ((size_t)(l0 + srow) * Bd + b) * K2H + skf;

    // LDS write target (frag-major): constant per thread
    const int kk_w   = skf >> 4;            // 0..3
    const int lh_w   = (skf & 15) >> 3;     // 0..1
    const int j0_w   = skf & 7;             // 0 or 4
    const int lane_w = lh_w * 32 + srow;
    const int slot_w = (lane_w ^ ((lane_w >> 3) & 7)) ^ kk_w;
    const uint32_t wb = (uint32_t)(kk_w * 1024 + slot_w * 16 + j0_w * 2);

    // LDS read base (frag-major): per kk offset = kk*1024 + (rb16 ^ (kk<<4))
    const uint32_t rb16 = (uint32_t)((lane ^ ((lane >> 3) & 7)) << 4);

    // B fragment base pointers for this wave's four column tiles
    const _Float16* Bp0 = Bh + ((size_t)(wn * 4 + 0) * 4096 + lane) * 8;
    const _Float16* Bp1 = Bh + ((size_t)(wn * 4 + 1) * 4096 + lane) * 8;
    const _Float16* Bp2 = Bh + ((size_t)(wn * 4 + 2) * 4096 + lane) * 8;
    const _Float16* Bp3 = Bh + ((size_t)(wn * 4 + 3) * 4096 + lane) * 8;

#define STAGE_CHUNK(dst, p)                                               \
    {                                                                     \
        f16x4 h_;                                                         \
        _Pragma("unroll")                                                 \
        for (int j = 0; j < 4; j++) h_[j] = (_Float16)((p)[j]);           \
        *(f16x4*)((dst) + wb) = h_;                                       \
    }

    // prologue: stage chunk 0 into buf 0
    {
        f32x4 p0 = __builtin_nontemporal_load((const f32x4*)gA);
        STAGE_CHUNK(AsB[0], p0)
    }

    for (int c = 0; c < 16; ++c) {
        __syncthreads();               // buf[c&1] staged; buf[(c+1)&1] free
        f32x4 pfA;
        if (c < 15) pfA = __builtin_nontemporal_load((const f32x4*)(gA + (c + 1) * 64));
        const char* hbase = AsB[c & 1];
#pragma unroll
        for (int kk = 0; kk < 4; ++kk) {
            const uint32_t ko = (uint32_t)(kk * 1024) + (rb16 ^ (uint32_t)(kk << 4));
            f16x8 a0 = *(const f16x8*)(hbase + ko);
            const size_t t = (size_t)(c * 4 + kk) * 512;
            f16x8 b0 = *(const f16x8*)(Bp0 + t);
            f16x8 b1 = *(const f16x8*)(Bp1 + t);
            f16x8 b2 = *(const f16x8*)(Bp2 + t);
            f16x8 b3 = *(const f16x8*)(Bp3 + t);
            __builtin_amdgcn_s_setprio(1);
            acc[0] = __builtin_amdgcn_mfma_f32_32x32x16_f16(a0, b0, acc[0], 0, 0, 0);
            acc[1] = __builtin_amdgcn_mfma_f32_32x32x16_f16(a0, b1, acc[1], 0, 0, 0);
            acc[2] = __builtin_amdgcn_mfma_f32_32x32x16_f16(a0, b2, acc[2], 0, 0, 0);
            acc[3] = __builtin_amdgcn_mfma_f32_32x32x16_f16(a0, b3, acc[3], 0, 0, 0);
            __builtin_amdgcn_s_setprio(0);
        }
        if (c < 15) STAGE_CHUNK(AsB[(c + 1) & 1], pfA)
    }

    // ---- epilogue: softmax over N (bias already in acc) + direct store ----
    // C/D layout: col n = lane&31, row rr = (r&3) + 8*(r>>2) + 4*hf (0..31)
#pragma unroll
    for (int r = 0; r < 16; r++) {
        float mx = fmaxf(fmaxf(acc[0][r], acc[1][r]), fmaxf(acc[2][r], acc[3][r]));
#pragma unroll
        for (int off = 1; off < 32; off <<= 1) mx = fmaxf(mx, __shfl_xor(mx, off));
        if (l31 == r) red[wn][(r & 3) + 8 * (r >> 2) + 4 * hf] = mx;
    }
    __syncthreads();
    if (tid < 32) {
        float v = red[0][tid];
#pragma unroll
        for (int w = 1; w < 8; w++) v = fmaxf(v, red[w][tid]);
        redc[tid] = v;
    }
    __syncthreads();

#pragma unroll
    for (int r = 0; r < 16; r++) {
        const int rr = (r & 3) + 8 * (r >> 2) + 4 * hf;
        const float rm = redc[rr];
        float s = 0.f;
#pragma unroll
        for (int nt = 0; nt < 4; nt++) {
            float e = __expf(acc[nt][r] - rm);
            acc[nt][r] = e;
            s += e;
        }
#pragma unroll
        for (int off = 1; off < 32; off <<= 1) s += __shfl_xor(s, off);
        if (l31 == r) red[wn][rr] = s;
    }
    __syncthreads();
    if (tid < 32) {
        float v = 0.f;
#pragma unroll
        for (int w = 0; w < 8; w++) v += red[w][tid];
        redc[tid] = 1.0f / v;
    }
    __syncthreads();

    float invr[16];
#pragma unroll
    for (int r = 0; r < 16; r++) invr[r] = redc[(r & 3) + 8 * (r >> 2) + 4 * hf];

#pragma unroll
    for (int nt = 0; nt < 4; nt++) {
        const int n = wn * 128 + nt * 32 + l31;
        float* op = out + ((size_t)b * Nd + n) * Ld + l0 + hf * 4;
#pragma unroll
        for (int g = 0; g < 4; g++) {
            float4 v = make_float4(acc[nt][g * 4 + 0] * invr[g * 4 + 0],
                                   acc[nt][g * 4 + 1] * invr[g * 4 + 1],
                                   acc[nt][g * 4 + 2] * invr[g * 4 + 2],
                                   acc[nt][g * 4 + 3] * invr[g * 4 + 3]);
            *(float4*)(op + 8 * g) = v;
        }
    }
}

// ---------------------------------------------------------------------------
// Workspace layout (2.1 MB + pad):
//   bias f32 [1024]        4 KB @ 0x0
//   Bh   f16 [1M + 2K pad] 2 MB + 4 KB @ 0x10000
// ---------------------------------------------------------------------------
extern "C" void kernel_launch(void* const* d_in, const int* in_sizes, int n_in,
                              void* d_out, int out_size, void* d_ws, size_t ws_size,
                              hipStream_t stream) {
    (void)in_sizes; (void)n_in; (void)out_size; (void)ws_size;

    const float* F    = (const float*)d_in[0];   // (768, 512)
    const float* enc  = (const float*)d_in[1];   // (512, 32, 1024)
    const float* Wlin = (const float*)d_in[2];   // (512, 1024)
    const float* blin = (const float*)d_in[3];   // (512,)
    const float* Wfea = (const float*)d_in[4];   // (512, 1024)
    const float* bfea = (const float*)d_in[5];   // (512,)
    const float* V    = (const float*)d_in[6];   // (256, 512)
    float* out = (float*)d_out;                  // (32, 1024, 512)

    char* ws = (char*)d_ws;
    float*    bias = (float*)ws;                  // 4 KB
    _Float16* Bh   = (_Float16*)(ws + 0x10000);   // 2 MB (+4 KB pad)

    build_wpack<<<dim3(32, 32), 256, 0, stream>>>(F, Wfea, V, Wlin, Bh);
    build_bias<<<dim3(1024), 64, 0, stream>>>(F, bfea, V, blin, bias);
    gemm_direct<<<dim3(512), 512, 0, stream>>>(enc, Bh, bias, out);
}

// Round 23
// 114.094 us; speedup vs baseline: 1.0182x; 1.0182x over previous
//
#include <hip/hip_runtime.h>
#include <hip/hip_bf16.h>
#include <math.h>

#define Hd   512
#define FPd  256
#define Ed   512
#define NFd  768
#define Ld   512
#define Bd   32
#define K2H  1024            // 2H
#define Nd   1024            // NF + FP
#define Md   (Ld * Bd)       // 16384

typedef _Float16 f16x8  __attribute__((ext_vector_type(8)));
typedef _Float16 f16x4  __attribute__((ext_vector_type(4)));
typedef float    f32x4  __attribute__((ext_vector_type(4)));
typedef float    f32x16 __attribute__((ext_vector_type(16)));

// ---------------------------------------------------------------------------
// Kernel 1: W_big PARTIAL build (e-split). grid (32 kx, 32 ny, 2 eh) =
// 2048 blocks x 256 thr = 8 blocks/CU = 32 waves/CU (full occupancy).
// Each block: 32n x 32k over a 256-e half; 1024 FMAs/thread (halved
// chains), 4 stage chunks (halved barriers). Writes fp32 partials.
// ---------------------------------------------------------------------------
__global__ __launch_bounds__(256)
void wpack_partial(const float* __restrict__ F,
                   const float* __restrict__ Wf,
                   const float* __restrict__ V,
                   const float* __restrict__ Wl,
                   float* __restrict__ Wpart) {
    __shared__ float fs[32][68];
    __shared__ float ws[64][36];
    const int tid = threadIdx.x;
    const int kx  = blockIdx.x;         // 0..31
    const int ny  = blockIdx.y;         // 0..31
    const int eh  = blockIdx.z;         // 0..1
    const int n0  = ny * 32;
    const int kl  = tid & 31;
    const int k   = kx * 32 + kl;
    const int ty  = tid >> 5;           // 0..7 -> 4 rows each

    const float* src;  const float* wsrc;
    if (n0 < NFd) { src = F + (size_t)n0 * Ed;          wsrc = Wf; }
    else          { src = V + (size_t)(n0 - NFd) * Hd;  wsrc = Wl; }
    const float* wbase = wsrc + kx * 32;

    float acc[4];
#pragma unroll
    for (int i = 0; i < 4; i++) acc[i] = 0.f;

    const int eb = eh * 256;
    for (int e0 = eb; e0 < eb + 256; e0 += 64) {
#pragma unroll
        for (int rep = 0; rep < 2; rep++) {
            int idx = rep * 256 + tid;
            int i   = idx >> 4;
            int q   = idx & 15;
            float4 v4 = *(const float4*)(src + (size_t)i * 512 + e0 + q * 4);
            *(float4*)(&fs[i][q * 4]) = v4;
        }
#pragma unroll
        for (int rep = 0; rep < 2; rep++) {
            int idx = rep * 256 + tid;
            int e   = idx >> 3;
            int q   = idx & 7;
            float4 v4 = *(const float4*)(wbase + (size_t)(e0 + e) * K2H + q * 4);
            *(float4*)(&ws[e][q * 4]) = v4;
        }
        __syncthreads();
#pragma unroll 4
        for (int kk = 0; kk < 64; kk += 4) {
            float w0 = ws[kk + 0][kl];
            float w1 = ws[kk + 1][kl];
            float w2 = ws[kk + 2][kl];
            float w3 = ws[kk + 3][kl];
#pragma unroll
            for (int i = 0; i < 4; i++) {
                float4 f4 = *(const float4*)(&fs[ty * 4 + i][kk]);
                acc[i] += f4.x * w0 + f4.y * w1 + f4.z * w2 + f4.w * w3;
            }
        }
        __syncthreads();
    }
    float* dst = Wpart + (size_t)eh * (Nd * K2H);
#pragma unroll
    for (int i = 0; i < 4; i++)
        dst[(size_t)(n0 + ty * 4 + i) * K2H + k] = acc[i];
}

// ---------------------------------------------------------------------------
// Kernel 1c: combine partials -> fp16 B frags.
// 512 blocks (ny 0..31, kx2 0..15) x 256 thr; block = 32n x 64k region.
// Frag layout (gemm-matching): fo = ((ntile*64 + t)*64 + lane)*8,
//   ntile = ny, t = kx2*4 + ksl, n = ny*32+(lane&31),
//   k = t*16+(lane>>5)*8+j = kx2*64 + kf + j.
// ---------------------------------------------------------------------------
__global__ __launch_bounds__(256)
void combine_wpack(const float* __restrict__ Wpart,
                   _Float16* __restrict__ Bh) {
    __shared__ float wtile[32][68];
    const int tid = threadIdx.x;
    const int bid = blockIdx.x;
    const int ny  = bid >> 4;
    const int kx2 = bid & 15;
    const int n0  = ny * 32;
    const int k0  = kx2 * 64;

    // load + add: 32 rows x 64 k, 8 floats/thread
    {
        const int row = tid >> 3;
        const int kq  = (tid & 7) * 8;
        const size_t off = (size_t)(n0 + row) * K2H + k0 + kq;
        f32x4 a0 = *(const f32x4*)(Wpart + off);
        f32x4 a1 = *(const f32x4*)(Wpart + off + 4);
        f32x4 b0 = *(const f32x4*)(Wpart + (size_t)(Nd * K2H) + off);
        f32x4 b1 = *(const f32x4*)(Wpart + (size_t)(Nd * K2H) + off + 4);
        *(f32x4*)(&wtile[row][kq])     = a0 + b0;
        *(f32x4*)(&wtile[row][kq + 4]) = a1 + b1;
    }
    __syncthreads();
    {
        const int lane = tid & 63;
        const int ksl  = tid >> 6;            // 0..3
        const int nl   = lane & 31;
        const int kf   = ksl * 16 + (lane >> 5) * 8;
        float w[8];
        *(float4*)(w)     = *(const float4*)(&wtile[nl][kf]);
        *(float4*)(w + 4) = *(const float4*)(&wtile[nl][kf + 4]);
        f16x8 h;
#pragma unroll
        for (int j = 0; j < 8; j++) h[j] = (_Float16)w[j];
        const size_t fo = ((size_t)(ny * 64 + kx2 * 4 + ksl) * 64 + lane) * 8;
        *(f16x8*)(Bh + fo) = h;
    }
}

// ---------------------------------------------------------------------------
// Kernel 1b: bias_big[n]
// ---------------------------------------------------------------------------
__global__ __launch_bounds__(64)
void build_bias(const float* __restrict__ F, const float* __restrict__ bf,
                const float* __restrict__ V, const float* __restrict__ bl,
                float* __restrict__ bias) {
    const int n    = blockIdx.x;
    const int lane = threadIdx.x;
    const float* row; const float* bsrc;
    if (n < NFd) { row = F + (size_t)n * Ed;          bsrc = bf; }
    else         { row = V + (size_t)(n - NFd) * Hd;  bsrc = bl; }
    float a = 0.f;
#pragma unroll
    for (int rep = 0; rep < 8; rep++) {
        int e = rep * 64 + lane;
        a += row[e] * bsrc[e];
    }
#pragma unroll
    for (int off = 1; off < 64; off <<= 1) a += __shfl_xor(a, off);
    if (lane == 0) bias[n] = a;
}

// ---------------------------------------------------------------------------
// Kernel 2 (R20 exact, best measured 70.1 us): GEMM (fp16 x fp16) + fused
// softmax + direct transposed store. NT enc loads, 2-deep B register
// pipeline, setprio around MFMA cluster, frag-major conflict-free LDS A.
// ---------------------------------------------------------------------------
__global__ __launch_bounds__(1024)
void gemm_direct(const float* __restrict__ enc,
                 const _Float16* __restrict__ Bh,
                 const float* __restrict__ bias,
                 float* __restrict__ out) {
    __shared__ char AsB[2][8192];      // per buf: single fp16 plane
    __shared__ float red[16][64];
    __shared__ float redc[64];

    const int tid  = threadIdx.x;
    const int lane = tid & 63;
    const int wn   = tid >> 6;         // wave 0..15 -> 64-col block
    const int hf   = lane >> 5;
    const int l31  = lane & 31;
    const int b    = blockIdx.x >> 3;  // 0..31
    const int l0   = (blockIdx.x & 7) * 64;

    // bias folded into accumulator init
    float bv[2];
#pragma unroll
    for (int nt = 0; nt < 2; nt++) bv[nt] = bias[wn * 64 + nt * 32 + l31];
    f32x16 acc[2][2];
#pragma unroll
    for (int ms = 0; ms < 2; ms++)
#pragma unroll
        for (int nt = 0; nt < 2; nt++)
#pragma unroll
            for (int r = 0; r < 16; r++) acc[ms][nt][r] = bv[nt];

    // global staging map: thread -> (row = tid>>4 in 0..63, 4 k at (tid&15)*4)
    const int srow = tid >> 4;
    const int skf  = (tid & 15) * 4;
    const float* gA = enc + ((size_t)(l0 + srow) * Bd + b) * K2H + skf;

    // LDS write target (frag-major): constant per thread
    const int kk_w   = skf >> 4;            // 0..3
    const int lh_w   = (skf & 15) >> 3;     // 0..1
    const int j0_w   = skf & 7;             // 0 or 4
    const int lane_w = lh_w * 32 + (srow & 31);
    const int slot_w = lane_w ^ ((lane_w >> 3) & 7) ^ kk_w;
    const uint32_t wb = (uint32_t)((srow >> 5) * 4096 + kk_w * 1024 + slot_w * 16 + j0_w * 2);

    // LDS read base (frag-major): per kk offset = kk*1024 + (rb16 ^ (kk<<4))
    const uint32_t rb16 = (uint32_t)((lane ^ ((lane >> 3) & 7)) << 4);

    // B fragment base pointers for this wave's two column tiles
    const _Float16* Bp0 = Bh + ((size_t)(wn * 2 + 0) * 4096 + lane) * 8;
    const _Float16* Bp1 = Bh + ((size_t)(wn * 2 + 1) * 4096 + lane) * 8;

#define STAGE_CHUNK(dst, p)                                               \
    {                                                                     \
        f16x4 h_;                                                         \
        _Pragma("unroll")                                                 \
        for (int j = 0; j < 4; j++) h_[j] = (_Float16)((p)[j]);           \
        *(f16x4*)((dst) + wb) = h_;                                       \
    }

    // prologue: stage chunk 0; preload B(t=0) and B(t=1)
    {
        f32x4 p0 = __builtin_nontemporal_load((const f32x4*)gA);
        STAGE_CHUNK(AsB[0], p0)
    }
    f16x8 b_cur0 = *(const f16x8*)(Bp0);
    f16x8 b_cur1 = *(const f16x8*)(Bp1);
    f16x8 b_nx0  = *(const f16x8*)(Bp0 + 512);
    f16x8 b_nx1  = *(const f16x8*)(Bp1 + 512);

    for (int c = 0; c < 16; ++c) {
        __syncthreads();               // buf[c&1] staged; buf[(c+1)&1] free
        f32x4 pfA;
        if (c < 15) pfA = __builtin_nontemporal_load((const f32x4*)(gA + (c + 1) * 64));
        const char* hbase = AsB[c & 1];
#pragma unroll
        for (int kk = 0; kk < 4; ++kk) {
            const uint32_t ko = (uint32_t)(kk * 1024) + (rb16 ^ (uint32_t)(kk << 4));
            f16x8 a0 = *(const f16x8*)(hbase + ko);
            f16x8 a1 = *(const f16x8*)(hbase + 4096 + ko);
            // issue t+2 B loads (2-deep; Bh padded so t+2<=65 is in-bounds)
            const size_t t2 = (size_t)(c * 4 + kk + 2) * 512;
            f16x8 b_n20 = *(const f16x8*)(Bp0 + t2);
            f16x8 b_n21 = *(const f16x8*)(Bp1 + t2);
            __builtin_amdgcn_s_setprio(1);
            acc[0][0] = __builtin_amdgcn_mfma_f32_32x32x16_f16(a0, b_cur0, acc[0][0], 0, 0, 0);
            acc[1][0] = __builtin_amdgcn_mfma_f32_32x32x16_f16(a1, b_cur0, acc[1][0], 0, 0, 0);
            acc[0][1] = __builtin_amdgcn_mfma_f32_32x32x16_f16(a0, b_cur1, acc[0][1], 0, 0, 0);
            acc[1][1] = __builtin_amdgcn_mfma_f32_32x32x16_f16(a1, b_cur1, acc[1][1], 0, 0, 0);
            __builtin_amdgcn_s_setprio(0);
            b_cur0 = b_nx0; b_cur1 = b_nx1;
            b_nx0 = b_n20;  b_nx1 = b_n21;
        }
        if (c < 15) STAGE_CHUNK(AsB[(c + 1) & 1], pfA)
    }

    // ---- epilogue: softmax over N (bias already in acc) + direct store ----
    // C/D layout: col n = lane&31, row rr = (r&3) + 8*(r>>2) + 4*hf
#pragma unroll
    for (int ms = 0; ms < 2; ms++) {
#pragma unroll
        for (int r = 0; r < 16; r++) {
            float mx = fmaxf(acc[ms][0][r], acc[ms][1][r]);
#pragma unroll
            for (int off = 1; off < 32; off <<= 1) mx = fmaxf(mx, __shfl_xor(mx, off));
            if (l31 == r) red[wn][ms * 32 + (r & 3) + 8 * (r >> 2) + 4 * hf] = mx;
        }
    }
    __syncthreads();
    if (tid < 64) {
        float v = red[0][tid];
#pragma unroll
        for (int w = 1; w < 16; w++) v = fmaxf(v, red[w][tid]);
        redc[tid] = v;
    }
    __syncthreads();

#pragma unroll
    for (int ms = 0; ms < 2; ms++) {
#pragma unroll
        for (int r = 0; r < 16; r++) {
            const int rr = ms * 32 + (r & 3) + 8 * (r >> 2) + 4 * hf;
            const float rm = redc[rr];
            float s = 0.f;
#pragma unroll
            for (int nt = 0; nt < 2; nt++) {
                float e = __expf(acc[ms][nt][r] - rm);
                acc[ms][nt][r] = e;
                s += e;
            }
#pragma unroll
            for (int off = 1; off < 32; off <<= 1) s += __shfl_xor(s, off);
            if (l31 == r) red[wn][rr] = s;
        }
    }
    __syncthreads();
    if (tid < 64) {
        float v = 0.f;
#pragma unroll
        for (int w = 0; w < 16; w++) v += red[w][tid];
        redc[tid] = 1.0f / v;
    }
    __syncthreads();

#pragma unroll
    for (int ms = 0; ms < 2; ms++) {
        float invr[16];
#pragma unroll
        for (int r = 0; r < 16; r++)
            invr[r] = redc[ms * 32 + (r & 3) + 8 * (r >> 2) + 4 * hf];
#pragma unroll
        for (int nt = 0; nt < 2; nt++) {
            const int n = wn * 64 + nt * 32 + l31;
            float* op = out + ((size_t)b * Nd + n) * Ld + l0 + ms * 32 + hf * 4;
#pragma unroll
            for (int g = 0; g < 4; g++) {
                float4 v = make_float4(acc[ms][nt][g * 4 + 0] * invr[g * 4 + 0],
                                       acc[ms][nt][g * 4 + 1] * invr[g * 4 + 1],
                                       acc[ms][nt][g * 4 + 2] * invr[g * 4 + 2],
                                       acc[ms][nt][g * 4 + 3] * invr[g * 4 + 3]);
                *(float4*)(op + 8 * g) = v;
            }
        }
    }
}

// ---------------------------------------------------------------------------
// Workspace layout (10.3 MB):
//   bias  f32 [1024]            4 KB @ 0x0
//   Bh    f16 [1M + 2K pad]     2 MB + 4 KB @ 0x10000
//   Wpart f32 [2][1024][1024]   8 MB @ 0x220000
// ---------------------------------------------------------------------------
extern "C" void kernel_launch(void* const* d_in, const int* in_sizes, int n_in,
                              void* d_out, int out_size, void* d_ws, size_t ws_size,
                              hipStream_t stream) {
    (void)in_sizes; (void)n_in; (void)out_size; (void)ws_size;

    const float* F    = (const float*)d_in[0];   // (768, 512)
    const float* enc  = (const float*)d_in[1];   // (512, 32, 1024)
    const float* Wlin = (const float*)d_in[2];   // (512, 1024)
    const float* blin = (const float*)d_in[3];   // (512,)
    const float* Wfea = (const float*)d_in[4];   // (512, 1024)
    const float* bfea = (const float*)d_in[5];   // (512,)
    const float* V    = (const float*)d_in[6];   // (256, 512)
    float* out = (float*)d_out;                  // (32, 1024, 512)

    char* ws = (char*)d_ws;
    float*    bias  = (float*)ws;                  // 4 KB
    _Float16* Bh    = (_Float16*)(ws + 0x10000);   // 2 MB (+4 KB pad)
    float*    Wpart = (float*)(ws + 0x220000);     // 8 MB

    wpack_partial<<<dim3(32, 32, 2), 256, 0, stream>>>(F, Wfea, V, Wlin, Wpart);
    build_bias<<<dim3(1024), 64, 0, stream>>>(F, bfea, V, blin, bias);
    combine_wpack<<<dim3(512), 256, 0, stream>>>(Wpart, Bh);
    gemm_direct<<<dim3(256), 1024, 0, stream>>>(enc, Bh, bias, out);
}